// Round 1
// baseline (428.330 us; speedup 1.0000x reference)
//
#include <hip/hip_runtime.h>
#include <stdint.h>

#define EPSF 1e-8f

typedef __attribute__((ext_vector_type(4))) float f32x4;
typedef __attribute__((ext_vector_type(8))) short s16x8;

__device__ __forceinline__ uint32_t f2bf(float f) {
    uint32_t u = __builtin_bit_cast(uint32_t, f);
    return (u + 0x7FFFu + ((u >> 16) & 1u)) >> 16;  // RNE fp32 -> bf16 bits
}

// ---------------------------------------------------------------------------
// K1: per-batch moments + bf16-MFMA Gram -> feats (all except median)
// grid 512 (1 block per batch), 256 threads (4 waves)
// ---------------------------------------------------------------------------
__global__ __launch_bounds__(256) void k1_stats_gram(const float* __restrict__ x,
                                                     float* __restrict__ feats) {
    const int b = blockIdx.x;
    const int tid = threadIdx.x;
    const int lane = tid & 63;
    const int w = tid >> 6;

    __shared__ float lds_f[64][64];      // fp32 tile [t][c]
    __shared__ uint4 lds_b4[64 * 8];     // bf16 tile [c][t], swizzled, 128B rows
    __shared__ float red[6][4][64];
    __shared__ float Gs[64][64];
    __shared__ float mu_s[64], is_s[64];

    char* ldsb = (char*)lds_b4;

    float S1 = 0.f, S2 = 0.f, S3 = 0.f, S4 = 0.f;
    float mx = -INFINITY, mn = INFINITY;
    f32x4 acc0 = {0.f, 0.f, 0.f, 0.f};
    f32x4 acc1 = {0.f, 0.f, 0.f, 0.f};
    f32x4 acc2 = {0.f, 0.f, 0.f, 0.f};

    const int mc = tid & 63, mq = tid >> 6;
    const int c2 = (tid & 15) + ((tid >> 6) << 4);   // conversion: channel
    const int t0 = ((tid >> 4) & 3) << 3;            // conversion: t-strip base

    // upper-triangle 4x4 tile enumeration packed 2 bits/entry
    const uint32_t ciPack = 0xE9500u;   // {0,0,0,0,1,1,1,2,2,3}
    const uint32_t diPack = 0xFB9E4u;   // {0,1,2,3,1,2,3,2,3,3}
    const int nt = (w < 2) ? 3 : 2;     // tiles per wave: w, w+4, w+8
    int cA_[3], cB_[3];
#pragma unroll
    for (int s = 0; s < 3; ++s) {
        int idx = w + s * 4;
        if (idx > 9) idx = 9;
        int ci = (ciPack >> (2 * idx)) & 3;
        int di = (diPack >> (2 * idx)) & 3;
        cA_[s] = ci * 16 + (lane & 15);
        cB_[s] = di * 16 + (lane & 15);
    }

    const float* xb = x + (size_t)b * (2048 * 64);

    for (int tile = 0; tile < 32; ++tile) {
        float4 v[4];
#pragma unroll
        for (int i = 0; i < 4; ++i) {
            int r = (tid >> 4) + (i << 4);
            v[i] = *(const float4*)(xb + (size_t)tile * 4096 + r * 64 + ((tid & 15) << 2));
        }
        __syncthreads();  // prior tile fully consumed
#pragma unroll
        for (int i = 0; i < 4; ++i) {
            int r = (tid >> 4) + (i << 4);
            *(float4*)&lds_f[r][(tid & 15) << 2] = v[i];
        }
        __syncthreads();
        // moments: channel mc, t-quarter mq
#pragma unroll
        for (int j = 0; j < 16; ++j) {
            float vv = lds_f[(mq << 4) + j][mc];
            S1 += vv;
            float v2 = vv * vv;
            S2 += v2; S3 += v2 * vv; S4 += v2 * v2;
            mx = fmaxf(mx, vv); mn = fminf(mn, vv);
        }
        // convert two 8-t strips of channel c2 to bf16 [c][t] swizzled
#pragma unroll
        for (int sg = 0; sg < 2; ++sg) {
            int tt = t0 + (sg << 5);
            uint32_t b0 = f2bf(lds_f[tt + 0][c2]);
            uint32_t b1 = f2bf(lds_f[tt + 1][c2]);
            uint32_t b2v = f2bf(lds_f[tt + 2][c2]);
            uint32_t b3 = f2bf(lds_f[tt + 3][c2]);
            uint32_t b4 = f2bf(lds_f[tt + 4][c2]);
            uint32_t b5 = f2bf(lds_f[tt + 5][c2]);
            uint32_t b6 = f2bf(lds_f[tt + 6][c2]);
            uint32_t b7 = f2bf(lds_f[tt + 7][c2]);
            uint32_t off = (uint32_t)(c2 * 128) + (((uint32_t)(tt * 2)) ^ (uint32_t)((c2 & 7) << 4));
            *(uint4*)(ldsb + off) = make_uint4(b0 | (b1 << 16), b2v | (b3 << 16),
                                               b4 | (b5 << 16), b6 | (b7 << 16));
        }
        __syncthreads();
        // MFMA: G += X^T X for this 64-t tile (2 k-steps of 32)
#pragma unroll
        for (int kb = 0; kb < 2; ++kb) {
            const uint32_t tb = ((uint32_t)(lane >> 4) << 4) | ((uint32_t)kb << 6);
            {
                const s16x8 a = *(const s16x8*)(ldsb + (uint32_t)(cA_[0] * 128) + (tb ^ (uint32_t)((cA_[0] & 7) << 4)));
                const s16x8 bb = *(const s16x8*)(ldsb + (uint32_t)(cB_[0] * 128) + (tb ^ (uint32_t)((cB_[0] & 7) << 4)));
                acc0 = __builtin_amdgcn_mfma_f32_16x16x32_bf16(a, bb, acc0, 0, 0, 0);
            }
            {
                const s16x8 a = *(const s16x8*)(ldsb + (uint32_t)(cA_[1] * 128) + (tb ^ (uint32_t)((cA_[1] & 7) << 4)));
                const s16x8 bb = *(const s16x8*)(ldsb + (uint32_t)(cB_[1] * 128) + (tb ^ (uint32_t)((cB_[1] & 7) << 4)));
                acc1 = __builtin_amdgcn_mfma_f32_16x16x32_bf16(a, bb, acc1, 0, 0, 0);
            }
            if (nt == 3) {
                const s16x8 a = *(const s16x8*)(ldsb + (uint32_t)(cA_[2] * 128) + (tb ^ (uint32_t)((cA_[2] & 7) << 4)));
                const s16x8 bb = *(const s16x8*)(ldsb + (uint32_t)(cB_[2] * 128) + (tb ^ (uint32_t)((cB_[2] & 7) << 4)));
                acc2 = __builtin_amdgcn_mfma_f32_16x16x32_bf16(a, bb, acc2, 0, 0, 0);
            }
        }
    }

    // store Gram tiles to LDS (D layout: col=lane&15, row=4*(lane>>4)+reg  [m89])
    {
        const int r15 = lane & 15, rq = lane >> 4;
#pragma unroll
        for (int s = 0; s < 3; ++s) {
            if (s == 2 && nt < 3) continue;
            int idx = w + s * 4;
            int ci = (ciPack >> (2 * idx)) & 3;
            int di = (diPack >> (2 * idx)) & 3;
            f32x4 a = (s == 0) ? acc0 : ((s == 1) ? acc1 : acc2);
#pragma unroll
            for (int r = 0; r < 4; ++r)
                Gs[ci * 16 + rq * 4 + r][di * 16 + r15] = a[r];
        }
    }
    red[0][mq][mc] = S1; red[1][mq][mc] = S2; red[2][mq][mc] = S3; red[3][mq][mc] = S4;
    red[4][mq][mc] = mx; red[5][mq][mc] = mn;
    __syncthreads();

    if (tid < 64) {
        float s1 = 0.f, s2 = 0.f, s3 = 0.f, s4 = 0.f, ma = -INFINITY, mi = INFINITY;
#pragma unroll
        for (int q = 0; q < 4; ++q) {
            s1 += red[0][q][tid]; s2 += red[1][q][tid];
            s3 += red[2][q][tid]; s4 += red[3][q][tid];
            ma = fmaxf(ma, red[4][q][tid]); mi = fminf(mi, red[5][q][tid]);
        }
        const float Tf = 2048.0f;
        float mu = s1 / Tf;
        float css = fmaxf(s2 - Tf * mu * mu, 0.f);        // sum centered^2
        float sd = sqrtf(css / (Tf - 1.f));               // ddof=1
        float m3 = (s3 - 3.f * mu * s2 + 2.f * Tf * mu * mu * mu) / Tf;
        float m4 = (s4 - 4.f * mu * s3 + 6.f * mu * mu * s2 - 3.f * Tf * mu * mu * mu * mu) / Tf;
        float skew = m3 / (sd * sd * sd + EPSF);
        float kurt = m4 / (sd * sd * sd * sd + EPSF);
        float cv = sd / (fabsf(mu) + EPSF);
        float* fb = feats + (size_t)b * 2528;
        fb[tid] = mu; fb[64 + tid] = sd; fb[128 + tid] = ma; fb[192 + tid] = mi;
        fb[320 + tid] = skew; fb[384 + tid] = kurt; fb[448 + tid] = cv;
        mu_s[tid] = mu; is_s[tid] = 1.f / (sd + EPSF);
    }
    __syncthreads();

    for (int p = tid; p < 2016; p += 256) {
        int i = 0;
        while ((i + 1) * 63 - ((i + 1) * i) / 2 <= p) ++i;
        int j = i + 1 + (p - (i * 63 - (i * (i - 1)) / 2));
        float num = Gs[i][j] - 2048.0f * mu_s[i] * mu_s[j];
        float cr = num * is_s[i] * is_s[j] * (1.0f / 2047.0f);
        feats[(size_t)b * 2528 + 512 + p] = cr;
    }
}

// ---------------------------------------------------------------------------
// K2: median via 2-pass radix select on bf16 keys. grid 4096 = 512 b x 8 cgrp
// ---------------------------------------------------------------------------
__global__ __launch_bounds__(256) void k2_median(const float* __restrict__ x,
                                                 float* __restrict__ feats) {
    const int bid = blockIdx.x;
    const int b = bid >> 3;
    const int c0 = (bid & 7) << 3;
    const int tid = threadIdx.x;

    __shared__ uint16_t keys[2048][8];
    __shared__ uint32_t hist[8][256];
    __shared__ uint32_t part[8][32];
    __shared__ uint32_t selB[8], selK[8];

    const float* xb = x + (size_t)b * (2048 * 64) + c0;

    for (int it = 0; it < 16; ++it) {
        int f = it * 256 + tid;
        int t = f >> 1;
        int c4 = (f & 1) << 2;
        float4 v = *(const float4*)(xb + (size_t)t * 64 + c4);
        uint32_t k0 = f2bf(v.x), k1 = f2bf(v.y), k2 = f2bf(v.z), k3 = f2bf(v.w);
        k0 = (k0 & 0x8000u) ? ((~k0) & 0xFFFFu) : (k0 | 0x8000u);
        k1 = (k1 & 0x8000u) ? ((~k1) & 0xFFFFu) : (k1 | 0x8000u);
        k2 = (k2 & 0x8000u) ? ((~k2) & 0xFFFFu) : (k2 | 0x8000u);
        k3 = (k3 & 0x8000u) ? ((~k3) & 0xFFFFu) : (k3 | 0x8000u);
        *(uint2*)&keys[t][c4] = make_uint2(k0 | (k1 << 16), k2 | (k3 << 16));
    }
#pragma unroll
    for (int m = 0; m < 8; ++m) ((uint32_t*)hist)[tid + 256 * m] = 0;
    __syncthreads();

    const int s = tid & 7, li = tid >> 3;   // 32 threads per series
    for (int j = 0; j < 64; ++j) {
        uint32_t k = keys[li + (j << 5)][s];
        atomicAdd(&hist[s][k >> 8], 1u);
    }
    __syncthreads();
    {
        uint32_t ps = 0;
#pragma unroll
        for (int q = 0; q < 8; ++q) ps += hist[s][li * 8 + q];
        part[s][li] = ps;
    }
    __syncthreads();
    if (li == 0) {
        int k = 1023;  // (T-1)//2
        int seg = 0;
        while (k >= (int)part[s][seg]) { k -= part[s][seg]; ++seg; }
        int bin = seg * 8;
        while (k >= (int)hist[s][bin]) { k -= hist[s][bin]; ++bin; }
        selB[s] = (uint32_t)bin; selK[s] = (uint32_t)k;
    }
    __syncthreads();
#pragma unroll
    for (int m = 0; m < 8; ++m) ((uint32_t*)hist)[tid + 256 * m] = 0;
    __syncthreads();
    const uint32_t B1 = selB[s];
    for (int j = 0; j < 64; ++j) {
        uint32_t k = keys[li + (j << 5)][s];
        if ((k >> 8) == B1) atomicAdd(&hist[s][k & 255u], 1u);
    }
    __syncthreads();
    {
        uint32_t ps = 0;
#pragma unroll
        for (int q = 0; q < 8; ++q) ps += hist[s][li * 8 + q];
        part[s][li] = ps;
    }
    __syncthreads();
    if (li == 0) {
        int k = (int)selK[s];
        int seg = 0;
        while (k >= (int)part[s][seg]) { k -= part[s][seg]; ++seg; }
        int bin = seg * 8;
        while (k >= (int)hist[s][bin]) { k -= hist[s][bin]; ++bin; }
        uint32_t key16 = (B1 << 8) | (uint32_t)bin;
        uint32_t bf = (key16 & 0x8000u) ? (key16 ^ 0x8000u) : ((~key16) & 0xFFFFu);
        float val = __builtin_bit_cast(float, bf << 16);
        feats[(size_t)b * 2528 + 256 + c0 + s] = val;
    }
}

// ---------------------------------------------------------------------------
// K3: h1-partial = feats @ W1^T, fp32, 64x64 tiles, 4x4/thread, k-split z=4
// grid (8 jt, 8 bt, 4 z)
// ---------------------------------------------------------------------------
__global__ __launch_bounds__(256) void k3_gemm1(const float* __restrict__ feats,
                                                const float* __restrict__ W1,
                                                float* __restrict__ C1p) {
    const int jt = blockIdx.x, bt = blockIdx.y, z = blockIdx.z;
    const int tid = threadIdx.x;
    __shared__ float As[64][33], Bs[64][33];
    const int k0 = z * 640;
    const int kend = k0 + ((z == 3) ? 608 : 640);
    const int tx = tid & 15, ty = tid >> 4;
    float acc[4][4] = {};

    for (int kc = k0; kc < kend; kc += 32) {
        __syncthreads();
#pragma unroll
        for (int i = 0; i < 2; ++i) {
            int f = tid + (i << 8);
            int r = f >> 3;
            int c4 = (f & 7) << 2;
            float4 va = *(const float4*)(feats + (size_t)(bt * 64 + r) * 2528 + kc + c4);
            float4 vb = *(const float4*)(W1 + (size_t)(jt * 64 + r) * 2528 + kc + c4);
            As[r][c4] = va.x; As[r][c4 + 1] = va.y; As[r][c4 + 2] = va.z; As[r][c4 + 3] = va.w;
            Bs[r][c4] = vb.x; Bs[r][c4 + 1] = vb.y; Bs[r][c4 + 2] = vb.z; Bs[r][c4 + 3] = vb.w;
        }
        __syncthreads();
#pragma unroll
        for (int kk = 0; kk < 32; ++kk) {
            float a[4], bb[4];
#pragma unroll
            for (int m = 0; m < 4; ++m) { a[m] = As[ty * 4 + m][kk]; bb[m] = Bs[tx * 4 + m][kk]; }
#pragma unroll
            for (int m = 0; m < 4; ++m)
#pragma unroll
                for (int n = 0; n < 4; ++n)
                    acc[m][n] += a[m] * bb[n];
        }
    }
    float* dst = C1p + (size_t)z * 262144;
#pragma unroll
    for (int m = 0; m < 4; ++m) {
        float4 o = make_float4(acc[m][0], acc[m][1], acc[m][2], acc[m][3]);
        *(float4*)(dst + (size_t)(bt * 64 + ty * 4 + m) * 512 + jt * 64 + tx * 4) = o;
    }
}

// ---------------------------------------------------------------------------
// K4: h2 = relu(sum_z C1p + b1) @ W2^T + b2, then LayerNorm. grid 64 (8 rows ea)
// ---------------------------------------------------------------------------
__global__ __launch_bounds__(256) void k4_gemm2_ln(const float* __restrict__ C1p,
                                                   const float* __restrict__ b1,
                                                   const float* __restrict__ W2,
                                                   const float* __restrict__ b2,
                                                   const float* __restrict__ gamma,
                                                   const float* __restrict__ beta,
                                                   float* __restrict__ out) {
    const int bt = blockIdx.x;
    const int tid = threadIdx.x;
    __shared__ float h1s[8][512];
    __shared__ float W2s[256][33];
    __shared__ float h2s[8][256];
    __shared__ float mu_s[8], rs_s[8];

#pragma unroll
    for (int m = 0; m < 16; ++m) {
        int idx = tid + (m << 8);
        int r = idx >> 9, k = idx & 511;
        size_t base = (size_t)(bt * 8 + r) * 512 + k;
        float v = C1p[base] + C1p[262144 + base] + C1p[524288 + base] + C1p[786432 + base] + b1[k];
        h1s[r][k] = fmaxf(v, 0.f);
    }
    float acc[8] = {};
    for (int kc = 0; kc < 512; kc += 32) {
        __syncthreads();
#pragma unroll
        for (int i = 0; i < 8; ++i) {
            int f = tid + (i << 8);
            int row = f >> 3, c4 = (f & 7) << 2;
            float4 v = *(const float4*)(W2 + (size_t)row * 512 + kc + c4);
            W2s[row][c4] = v.x; W2s[row][c4 + 1] = v.y; W2s[row][c4 + 2] = v.z; W2s[row][c4 + 3] = v.w;
        }
        __syncthreads();
#pragma unroll
        for (int kk = 0; kk < 32; ++kk) {
            float wv = W2s[tid][kk];
#pragma unroll
            for (int r = 0; r < 8; ++r) acc[r] += h1s[r][kc + kk] * wv;
        }
    }
    float bv = b2[tid];
    __syncthreads();
#pragma unroll
    for (int r = 0; r < 8; ++r) h2s[r][tid] = acc[r] + bv;
    __syncthreads();
    {
        int r = tid >> 5, l5 = tid & 31;
        float sum = 0.f;
#pragma unroll
        for (int jj = 0; jj < 8; ++jj) sum += h2s[r][l5 + jj * 32];
#pragma unroll
        for (int m = 16; m >= 1; m >>= 1) sum += __shfl_xor(sum, m);
        if (l5 == 0) mu_s[r] = sum * (1.0f / 256.0f);
    }
    __syncthreads();
    {
        int r = tid >> 5, l5 = tid & 31;
        float mu = mu_s[r];
        float sq = 0.f;
#pragma unroll
        for (int jj = 0; jj < 8; ++jj) { float d = h2s[r][l5 + jj * 32] - mu; sq += d * d; }
#pragma unroll
        for (int m = 16; m >= 1; m >>= 1) sq += __shfl_xor(sq, m);
        if (l5 == 0) rs_s[r] = rsqrtf(sq * (1.0f / 256.0f) + 1e-5f);
    }
    __syncthreads();
    float g = gamma[tid], be = beta[tid];
#pragma unroll
    for (int r = 0; r < 8; ++r) {
        float v = (h2s[r][tid] - mu_s[r]) * rs_s[r] * g + be;
        out[(size_t)(bt * 8 + r) * 256 + tid] = v;
    }
}

extern "C" void kernel_launch(void* const* d_in, const int* in_sizes, int n_in,
                              void* d_out, int out_size, void* d_ws, size_t ws_size,
                              hipStream_t stream) {
    const float* x = (const float*)d_in[0];
    const float* W1 = (const float*)d_in[1];
    const float* b1 = (const float*)d_in[2];
    const float* W2 = (const float*)d_in[3];
    const float* b2 = (const float*)d_in[4];
    const float* gamma = (const float*)d_in[5];
    const float* beta = (const float*)d_in[6];

    float* feats = (float*)d_ws;                       // 512 x 2528 fp32
    float* C1p = feats + (size_t)512 * 2528;           // 4 x 512 x 512 fp32
    float* out = (float*)d_out;

    k1_stats_gram<<<dim3(512), dim3(256), 0, stream>>>(x, feats);
    k2_median<<<dim3(4096), dim3(256), 0, stream>>>(x, feats);
    k3_gemm1<<<dim3(8, 8, 4), dim3(256), 0, stream>>>(feats, W1, C1p);
    k4_gemm2_ln<<<dim3(64), dim3(256), 0, stream>>>(C1p, b1, W2, b2, gamma, beta, out);
}

// Round 2
// 279.909 us; speedup vs baseline: 1.5302x; 1.5302x over previous
//
#include <hip/hip_runtime.h>
#include <stdint.h>

#define EPSF 1e-8f

typedef __attribute__((ext_vector_type(4))) float f32x4;
typedef __attribute__((ext_vector_type(8))) short s16x8;

__device__ __forceinline__ uint32_t f2bf(float f) {
    uint32_t u = __builtin_bit_cast(uint32_t, f);
    return (u + 0x7FFFu + ((u >> 16) & 1u)) >> 16;  // RNE fp32 -> bf16 bits
}

// ---------------------------------------------------------------------------
// K1: moments + bf16-MFMA Gram + coarse median histogram/selection
// grid 512 (1 block per batch), 512 threads (8 waves), 72.25 KB LDS (2/CU)
// ---------------------------------------------------------------------------
__global__ __launch_bounds__(512) void k1_stats_gram(const float* __restrict__ x,
                                                     float* __restrict__ feats,
                                                     uint2* __restrict__ sel) {
    const int b = blockIdx.x;
    const int tid = threadIdx.x;
    const int lane = tid & 63;

    __shared__ __align__(16) char smem[73984];
    float* lds_f = (float*)smem;                   // [64][64] fp32 tile [t][c]
    char* ldsb = smem + 16384;                     // bf16 tile [c][t] swizzled (8 KB)
    uint32_t* histP = (uint32_t*)(smem + 24576);   // [64][129] packed 2 bins/u32
    float* Gs = (float*)(smem + 57600);            // [64][64]
    float* red = (float*)smem;                     // post-loop alias: [8][6][64]
    float* mu_s = (float*)(smem + 12288);
    float* is_s = (float*)(smem + 12544);

    for (int i = tid; i < 64 * 129; i += 512) histP[i] = 0u;

    const int fc = tid & 15, r0 = tid >> 4;        // load mapping
    const int c2 = tid & 63, g = tid >> 6;         // convert mapping
    const uint32_t swz = (uint32_t)((c2 & 7) << 4);

    // Gram upper-tri 4x4 tile-grid enumeration (10 tiles over 8 waves)
    const uint32_t ciPack = 0xE9500u;  // {0,0,0,0,1,1,1,2,2,3}
    const uint32_t diPack = 0xFB9E4u;  // {0,1,2,3,1,2,3,2,3,3}
    const int w = tid >> 6;
    const int ci0 = (ciPack >> (2 * w)) & 3, di0 = (diPack >> (2 * w)) & 3;
    const bool has2 = (w < 2);
    const int idx1 = 8 + w;
    const int ci1 = (ciPack >> (2 * idx1)) & 3, di1 = (diPack >> (2 * idx1)) & 3;
    const int cA0 = ci0 * 16 + (lane & 15), cB0 = di0 * 16 + (lane & 15);
    const int cA1 = ci1 * 16 + (lane & 15), cB1 = di1 * 16 + (lane & 15);
    f32x4 acc0 = {0.f, 0.f, 0.f, 0.f};
    f32x4 acc1 = {0.f, 0.f, 0.f, 0.f};

    float S1 = 0.f, S2 = 0.f, S3 = 0.f, S4 = 0.f;
    float mx = -INFINITY, mn = INFINITY;

    const float* xb = x + (size_t)b * (2048 * 64);
    float4 v0 = *(const float4*)(xb + r0 * 64 + fc * 4);
    float4 v1 = *(const float4*)(xb + (r0 + 32) * 64 + fc * 4);

    for (int tile = 0; tile < 32; ++tile) {
        __syncthreads();  // B0: prior conversion reads of lds_f done; MFMA reads of ldsb done
        *(float4*)&lds_f[r0 * 64 + fc * 4] = v0;
        *(float4*)&lds_f[(r0 + 32) * 64 + fc * 4] = v1;
        __syncthreads();  // B1: lds_f ready
        if (tile + 1 < 32) {
            const float* xt = xb + (size_t)(tile + 1) * 4096;
            v0 = *(const float4*)(xt + r0 * 64 + fc * 4);     // prefetch overlaps convert
            v1 = *(const float4*)(xt + (r0 + 32) * 64 + fc * 4);
        }
        // convert + moments + coarse hist: thread owns channel c2, rows 8g..8g+7
        uint4 pkv;
        uint32_t pk[4];
#pragma unroll
        for (int j2 = 0; j2 < 4; ++j2) {
            float a0 = lds_f[(g * 8 + 2 * j2) * 64 + c2];
            float a1 = lds_f[(g * 8 + 2 * j2 + 1) * 64 + c2];
            S1 += a0 + a1;
            float q0 = a0 * a0, q1 = a1 * a1;
            S2 += q0 + q1;
            S3 += q0 * a0 + q1 * a1;
            S4 += q0 * q0 + q1 * q1;
            mx = fmaxf(mx, fmaxf(a0, a1));
            mn = fminf(mn, fminf(a0, a1));
            uint32_t u0 = f2bf(a0), u1 = f2bf(a1);
            pk[j2] = u0 | (u1 << 16);
            uint32_t k0 = (u0 & 0x8000u) ? ((~u0) & 0xFFFFu) : (u0 | 0x8000u);
            uint32_t k1 = (u1 & 0x8000u) ? ((~u1) & 0xFFFFu) : (u1 | 0x8000u);
            atomicAdd(&histP[c2 * 129 + ((k0 >> 8) >> 1)], 1u << (((k0 >> 8) & 1) * 16));
            atomicAdd(&histP[c2 * 129 + ((k1 >> 8) >> 1)], 1u << (((k1 >> 8) & 1) * 16));
        }
        pkv.x = pk[0]; pkv.y = pk[1]; pkv.z = pk[2]; pkv.w = pk[3];
        *(uint4*)(ldsb + (uint32_t)(c2 * 128) + (((uint32_t)(g * 16)) ^ swz)) = pkv;
        __syncthreads();  // B2: ldsb ready
#pragma unroll
        for (int kb = 0; kb < 2; ++kb) {
            const uint32_t tb = (uint32_t)(16 * (lane >> 4) + 64 * kb);
            s16x8 af = *(const s16x8*)(ldsb + (uint32_t)(cA0 * 128) + (tb ^ (uint32_t)((cA0 & 7) << 4)));
            s16x8 bf = *(const s16x8*)(ldsb + (uint32_t)(cB0 * 128) + (tb ^ (uint32_t)((cB0 & 7) << 4)));
            acc0 = __builtin_amdgcn_mfma_f32_16x16x32_bf16(af, bf, acc0, 0, 0, 0);
            if (has2) {
                s16x8 af1 = *(const s16x8*)(ldsb + (uint32_t)(cA1 * 128) + (tb ^ (uint32_t)((cA1 & 7) << 4)));
                s16x8 bf1 = *(const s16x8*)(ldsb + (uint32_t)(cB1 * 128) + (tb ^ (uint32_t)((cB1 & 7) << 4)));
                acc1 = __builtin_amdgcn_mfma_f32_16x16x32_bf16(af1, bf1, acc1, 0, 0, 0);
            }
        }
    }
    __syncthreads();  // loop done; lds_f dead -> red/mu_s alias safe

    // Gram tiles -> Gs (D layout: col=lane&15, row=4*(lane>>4)+reg)
    {
        const int r15 = lane & 15, rq = lane >> 4;
#pragma unroll
        for (int r = 0; r < 4; ++r)
            Gs[(ci0 * 16 + rq * 4 + r) * 64 + di0 * 16 + r15] = acc0[r];
        if (has2) {
#pragma unroll
            for (int r = 0; r < 4; ++r)
                Gs[(ci1 * 16 + rq * 4 + r) * 64 + di1 * 16 + r15] = acc1[r];
        }
    }
    red[(g * 6 + 0) * 64 + c2] = S1;
    red[(g * 6 + 1) * 64 + c2] = S2;
    red[(g * 6 + 2) * 64 + c2] = S3;
    red[(g * 6 + 3) * 64 + c2] = S4;
    red[(g * 6 + 4) * 64 + c2] = mx;
    red[(g * 6 + 5) * 64 + c2] = mn;
    __syncthreads();

    if (tid < 64) {
        float s1 = 0.f, s2 = 0.f, s3 = 0.f, s4 = 0.f, ma = -INFINITY, mi = INFINITY;
#pragma unroll
        for (int gg = 0; gg < 8; ++gg) {
            s1 += red[(gg * 6 + 0) * 64 + tid];
            s2 += red[(gg * 6 + 1) * 64 + tid];
            s3 += red[(gg * 6 + 2) * 64 + tid];
            s4 += red[(gg * 6 + 3) * 64 + tid];
            ma = fmaxf(ma, red[(gg * 6 + 4) * 64 + tid]);
            mi = fminf(mi, red[(gg * 6 + 5) * 64 + tid]);
        }
        const float Tf = 2048.0f;
        float mu = s1 / Tf;
        float css = fmaxf(s2 - Tf * mu * mu, 0.f);
        float sd = sqrtf(css / (Tf - 1.f));
        float m3 = (s3 - 3.f * mu * s2 + 2.f * Tf * mu * mu * mu) / Tf;
        float m4 = (s4 - 4.f * mu * s3 + 6.f * mu * mu * s2 - 3.f * Tf * mu * mu * mu * mu) / Tf;
        float skew = m3 / (sd * sd * sd + EPSF);
        float kurt = m4 / (sd * sd * sd * sd + EPSF);
        float cv = sd / (fabsf(mu) + EPSF);
        float* fb = feats + (size_t)b * 2528;
        fb[tid] = mu; fb[64 + tid] = sd; fb[128 + tid] = ma; fb[192 + tid] = mi;
        fb[320 + tid] = skew; fb[384 + tid] = kurt; fb[448 + tid] = cv;
        mu_s[tid] = mu; is_s[tid] = 1.f / (sd + EPSF);
        // coarse selection: rank 1023 over 256 packed bins
        int k = 1023, bin = -1;
        for (int bq = 0; bq < 128; ++bq) {
            uint32_t wd = histP[tid * 129 + bq];
            int c0n = (int)(wd & 0xFFFFu), c1n = (int)(wd >> 16);
            if (bin < 0) {
                if (k < c0n) bin = 2 * bq;
                else { k -= c0n; if (k < c1n) bin = 2 * bq + 1; else k -= c1n; }
            }
        }
        sel[b * 64 + tid] = make_uint2((uint32_t)bin, (uint32_t)k);
    }
    __syncthreads();

    for (int p = tid; p < 2016; p += 512) {
        int i = 0;
        while ((i + 1) * 63 - ((i + 1) * i) / 2 <= p) ++i;
        int j = i + 1 + (p - (i * 63 - (i * (i - 1)) / 2));
        float num = Gs[i * 64 + j] - 2048.0f * mu_s[i] * mu_s[j];
        float cr = num * is_s[i] * is_s[j] * (1.0f / 2047.0f);
        feats[(size_t)b * 2528 + 512 + p] = cr;
    }
}

// ---------------------------------------------------------------------------
// K2: median fine pass — one coalesced scan of x, predicated fine histogram
// grid 512 (1 block per batch), 512 threads, 33.5 KB LDS
// ---------------------------------------------------------------------------
__global__ __launch_bounds__(512) void k2_median(const float* __restrict__ x,
                                                 const uint2* __restrict__ sel,
                                                 float* __restrict__ feats) {
    const int b = blockIdx.x;
    const int tid = threadIdx.x;
    __shared__ uint32_t fh[64 * 129];
    __shared__ uint32_t selB_s[64], rank_s[64];

    for (int i = tid; i < 64 * 129; i += 512) fh[i] = 0u;
    if (tid < 64) {
        uint2 s = sel[b * 64 + tid];
        selB_s[tid] = s.x; rank_s[tid] = s.y;
    }
    __syncthreads();

    const int fc = tid & 15, r0 = tid >> 4;
    const float* xb = x + (size_t)b * (2048 * 64);
    const uint32_t sb0 = selB_s[fc * 4 + 0], sb1 = selB_s[fc * 4 + 1];
    const uint32_t sb2 = selB_s[fc * 4 + 2], sb3 = selB_s[fc * 4 + 3];

    for (int i = 0; i < 64; ++i) {
        float4 v = *(const float4*)(xb + (size_t)(r0 + 32 * i) * 64 + fc * 4);
#pragma unroll
        for (int cc = 0; cc < 4; ++cc) {
            float vf = (cc == 0) ? v.x : (cc == 1) ? v.y : (cc == 2) ? v.z : v.w;
            uint32_t sb = (cc == 0) ? sb0 : (cc == 1) ? sb1 : (cc == 2) ? sb2 : sb3;
            uint32_t u = f2bf(vf);
            uint32_t k = (u & 0x8000u) ? ((~u) & 0xFFFFu) : (u | 0x8000u);
            if ((k >> 8) == sb) {
                uint32_t fb = k & 255u;
                atomicAdd(&fh[(fc * 4 + cc) * 129 + (fb >> 1)], 1u << ((fb & 1u) * 16));
            }
        }
    }
    __syncthreads();

    if (tid < 64) {
        int k = (int)rank_s[tid], bin = -1;
        for (int bq = 0; bq < 128; ++bq) {
            uint32_t wd = fh[tid * 129 + bq];
            int c0n = (int)(wd & 0xFFFFu), c1n = (int)(wd >> 16);
            if (bin < 0) {
                if (k < c0n) bin = 2 * bq;
                else { k -= c0n; if (k < c1n) bin = 2 * bq + 1; else k -= c1n; }
            }
        }
        uint32_t key16 = (selB_s[tid] << 8) | (uint32_t)bin;
        uint32_t bf = (key16 & 0x8000u) ? (key16 ^ 0x8000u) : ((~key16) & 0xFFFFu);
        feats[(size_t)b * 2528 + 256 + tid] = __builtin_bit_cast(float, bf << 16);
    }
}

// ---------------------------------------------------------------------------
// K3: h1-partial = feats @ W1^T, fp32, 64x64 tiles, 4x4/thread, k-split z=4
// ---------------------------------------------------------------------------
__global__ __launch_bounds__(256) void k3_gemm1(const float* __restrict__ feats,
                                                const float* __restrict__ W1,
                                                float* __restrict__ C1p) {
    const int jt = blockIdx.x, bt = blockIdx.y, z = blockIdx.z;
    const int tid = threadIdx.x;
    __shared__ float As[64][33], Bs[64][33];
    const int k0 = z * 640;
    const int kend = k0 + ((z == 3) ? 608 : 640);
    const int tx = tid & 15, ty = tid >> 4;
    float acc[4][4] = {};

    for (int kc = k0; kc < kend; kc += 32) {
        __syncthreads();
#pragma unroll
        for (int i = 0; i < 2; ++i) {
            int f = tid + (i << 8);
            int r = f >> 3;
            int c4 = (f & 7) << 2;
            float4 va = *(const float4*)(feats + (size_t)(bt * 64 + r) * 2528 + kc + c4);
            float4 vb = *(const float4*)(W1 + (size_t)(jt * 64 + r) * 2528 + kc + c4);
            As[r][c4] = va.x; As[r][c4 + 1] = va.y; As[r][c4 + 2] = va.z; As[r][c4 + 3] = va.w;
            Bs[r][c4] = vb.x; Bs[r][c4 + 1] = vb.y; Bs[r][c4 + 2] = vb.z; Bs[r][c4 + 3] = vb.w;
        }
        __syncthreads();
#pragma unroll
        for (int kk = 0; kk < 32; ++kk) {
            float a[4], bb[4];
#pragma unroll
            for (int m = 0; m < 4; ++m) { a[m] = As[ty * 4 + m][kk]; bb[m] = Bs[tx * 4 + m][kk]; }
#pragma unroll
            for (int m = 0; m < 4; ++m)
#pragma unroll
                for (int n = 0; n < 4; ++n)
                    acc[m][n] += a[m] * bb[n];
        }
    }
    float* dst = C1p + (size_t)z * 262144;
#pragma unroll
    for (int m = 0; m < 4; ++m) {
        float4 o = make_float4(acc[m][0], acc[m][1], acc[m][2], acc[m][3]);
        *(float4*)(dst + (size_t)(bt * 64 + ty * 4 + m) * 512 + jt * 64 + tx * 4) = o;
    }
}

// ---------------------------------------------------------------------------
// K4: h2 = relu(sum_z C1p + b1) @ W2^T + b2, then LayerNorm. grid 64
// ---------------------------------------------------------------------------
__global__ __launch_bounds__(256) void k4_gemm2_ln(const float* __restrict__ C1p,
                                                   const float* __restrict__ b1,
                                                   const float* __restrict__ W2,
                                                   const float* __restrict__ b2,
                                                   const float* __restrict__ gamma,
                                                   const float* __restrict__ beta,
                                                   float* __restrict__ out) {
    const int bt = blockIdx.x;
    const int tid = threadIdx.x;
    __shared__ float h1s[8][512];
    __shared__ float W2s[256][33];
    __shared__ float h2s[8][256];
    __shared__ float mu_s[8], rs_s[8];

#pragma unroll
    for (int m = 0; m < 16; ++m) {
        int idx = tid + (m << 8);
        int r = idx >> 9, k = idx & 511;
        size_t base = (size_t)(bt * 8 + r) * 512 + k;
        float v = C1p[base] + C1p[262144 + base] + C1p[524288 + base] + C1p[786432 + base] + b1[k];
        h1s[r][k] = fmaxf(v, 0.f);
    }
    float acc[8] = {};
    for (int kc = 0; kc < 512; kc += 32) {
        __syncthreads();
#pragma unroll
        for (int i = 0; i < 8; ++i) {
            int f = tid + (i << 8);
            int row = f >> 3, c4 = (f & 7) << 2;
            float4 v = *(const float4*)(W2 + (size_t)row * 512 + kc + c4);
            W2s[row][c4] = v.x; W2s[row][c4 + 1] = v.y; W2s[row][c4 + 2] = v.z; W2s[row][c4 + 3] = v.w;
        }
        __syncthreads();
#pragma unroll
        for (int kk = 0; kk < 32; ++kk) {
            float wv = W2s[tid][kk];
#pragma unroll
            for (int r = 0; r < 8; ++r) acc[r] += h1s[r][kc + kk] * wv;
        }
    }
    float bv = b2[tid];
    __syncthreads();
#pragma unroll
    for (int r = 0; r < 8; ++r) h2s[r][tid] = acc[r] + bv;
    __syncthreads();
    {
        int r = tid >> 5, l5 = tid & 31;
        float sum = 0.f;
#pragma unroll
        for (int jj = 0; jj < 8; ++jj) sum += h2s[r][l5 + jj * 32];
#pragma unroll
        for (int m = 16; m >= 1; m >>= 1) sum += __shfl_xor(sum, m);
        if (l5 == 0) mu_s[r] = sum * (1.0f / 256.0f);
    }
    __syncthreads();
    {
        int r = tid >> 5, l5 = tid & 31;
        float mu = mu_s[r];
        float sq = 0.f;
#pragma unroll
        for (int jj = 0; jj < 8; ++jj) { float d = h2s[r][l5 + jj * 32] - mu; sq += d * d; }
#pragma unroll
        for (int m = 16; m >= 1; m >>= 1) sq += __shfl_xor(sq, m);
        if (l5 == 0) rs_s[r] = rsqrtf(sq * (1.0f / 256.0f) + 1e-5f);
    }
    __syncthreads();
    float g = gamma[tid], be = beta[tid];
#pragma unroll
    for (int r = 0; r < 8; ++r) {
        float v = (h2s[r][tid] - mu_s[r]) * rs_s[r] * g + be;
        out[(size_t)(bt * 8 + r) * 256 + tid] = v;
    }
}

extern "C" void kernel_launch(void* const* d_in, const int* in_sizes, int n_in,
                              void* d_out, int out_size, void* d_ws, size_t ws_size,
                              hipStream_t stream) {
    const float* x = (const float*)d_in[0];
    const float* W1 = (const float*)d_in[1];
    const float* b1 = (const float*)d_in[2];
    const float* W2 = (const float*)d_in[3];
    const float* b2 = (const float*)d_in[4];
    const float* gamma = (const float*)d_in[5];
    const float* beta = (const float*)d_in[6];

    float* feats = (float*)d_ws;                       // 512 x 2528 fp32
    float* C1p = feats + (size_t)512 * 2528;           // 4 x 512 x 512 fp32
    uint2* sel = (uint2*)(C1p + (size_t)4 * 512 * 512);
    float* out = (float*)d_out;

    k1_stats_gram<<<dim3(512), dim3(512), 0, stream>>>(x, feats, sel);
    k2_median<<<dim3(512), dim3(512), 0, stream>>>(x, sel, feats);
    k3_gemm1<<<dim3(8, 8, 4), dim3(256), 0, stream>>>(feats, W1, C1p);
    k4_gemm2_ln<<<dim3(64), dim3(256), 0, stream>>>(C1p, b1, W2, b2, gamma, beta, out);
}

// Round 3
// 266.563 us; speedup vs baseline: 1.6069x; 1.0501x over previous
//
#include <hip/hip_runtime.h>
#include <stdint.h>

#define EPSF 1e-8f

typedef __attribute__((ext_vector_type(4))) float f32x4;
typedef __attribute__((ext_vector_type(8))) short s16x8;

__device__ __forceinline__ uint32_t f2bf(float f) {
    uint32_t u = __builtin_bit_cast(uint32_t, f);
    return (u + 0x7FFFu + ((u >> 16) & 1u)) >> 16;  // RNE fp32 -> bf16 bits
}

__device__ __forceinline__ void gram_step(const char* pb, int lane,
                                          int cA0, int cB0, int cA1, int cB1, bool has2,
                                          f32x4& acc0, f32x4& acc1) {
#pragma unroll
    for (int kb = 0; kb < 2; ++kb) {
        const uint32_t tb = (uint32_t)(16 * (lane >> 4) + 64 * kb);
        s16x8 af = *(const s16x8*)(pb + (uint32_t)(cA0 * 128) + (tb ^ (uint32_t)((cA0 & 7) << 4)));
        s16x8 bf = *(const s16x8*)(pb + (uint32_t)(cB0 * 128) + (tb ^ (uint32_t)((cB0 & 7) << 4)));
        acc0 = __builtin_amdgcn_mfma_f32_16x16x32_bf16(af, bf, acc0, 0, 0, 0);
        if (has2) {
            s16x8 af1 = *(const s16x8*)(pb + (uint32_t)(cA1 * 128) + (tb ^ (uint32_t)((cA1 & 7) << 4)));
            s16x8 bf1 = *(const s16x8*)(pb + (uint32_t)(cB1 * 128) + (tb ^ (uint32_t)((cB1 & 7) << 4)));
            acc1 = __builtin_amdgcn_mfma_f32_16x16x32_bf16(af1, bf1, acc1, 0, 0, 0);
        }
    }
}

// ---------------------------------------------------------------------------
// K1: moments + bf16-MFMA Gram (dbuf, MFMA overlaps convert) + 7-bit coarse
// median histogram/selection. grid 512, 512 threads, 49.4 KB LDS (2/CU)
// ---------------------------------------------------------------------------
__global__ __launch_bounds__(512, 4) void k1_stats_gram(const float* __restrict__ x,
                                                        float* __restrict__ feats,
                                                        uint2* __restrict__ sel) {
    const int b = blockIdx.x;
    const int tid = threadIdx.x;
    const int lane = tid & 63;

    __shared__ __align__(16) char smem[49408];
    float* lds_f = (float*)smem;                   // [64][64] fp32 tile [t][c] (16384 B)
    char* ldsb = smem + 16384;                     // 2 x 8192 B bf16 [c][t] swizzled
    uint32_t* histP = (uint32_t*)(smem + 32768);   // [64][65] packed 2x u16 bins (16640 B)
    // post-loop aliases:
    float* Gs = (float*)(smem + 16384);            // [64][64] over ldsb
    float* red = (float*)smem;                     // [8][6][64] over lds_f
    float* mu_s = (float*)(smem + 12544);
    float* is_s = (float*)(smem + 12800);

    for (int i = tid; i < 64 * 65; i += 512) histP[i] = 0u;

    const int fc = tid & 15, r0 = tid >> 4;        // load mapping
    const int c2 = tid & 63, g = tid >> 6;         // convert mapping
    const uint32_t swz = (uint32_t)((c2 & 7) << 4);

    // Gram upper-tri 4x4 tile-grid enumeration (10 tiles over 8 waves)
    const uint32_t ciPack = 0xE9500u;  // {0,0,0,0,1,1,1,2,2,3}
    const uint32_t diPack = 0xFB9E4u;  // {0,1,2,3,1,2,3,2,3,3}
    const int w = tid >> 6;
    const int ci0 = (ciPack >> (2 * w)) & 3, di0 = (diPack >> (2 * w)) & 3;
    const bool has2 = (w < 2);
    const int idx1 = 8 + w;
    const int ci1 = (ciPack >> (2 * idx1)) & 3, di1 = (diPack >> (2 * idx1)) & 3;
    const int cA0 = ci0 * 16 + (lane & 15), cB0 = di0 * 16 + (lane & 15);
    const int cA1 = ci1 * 16 + (lane & 15), cB1 = di1 * 16 + (lane & 15);
    f32x4 acc0 = {0.f, 0.f, 0.f, 0.f};
    f32x4 acc1 = {0.f, 0.f, 0.f, 0.f};

    float S1 = 0.f, S2 = 0.f, S3 = 0.f, S4 = 0.f;
    float mx = -INFINITY, mn = INFINITY;

    const float* xb = x + (size_t)b * (2048 * 64);
    float4 v0 = *(const float4*)(xb + r0 * 64 + fc * 4);
    float4 v1 = *(const float4*)(xb + (r0 + 32) * 64 + fc * 4);
    __syncthreads();  // histP clear complete

    for (int tile = 0; tile < 32; ++tile) {
        // B0 also covers: prior convert done reading lds_f; MFMA(tile-2) done on ldsb[tile&1]
        *(float4*)&lds_f[r0 * 64 + fc * 4] = v0;
        *(float4*)&lds_f[(r0 + 32) * 64 + fc * 4] = v1;
        __syncthreads();  // B1: lds_f ready; ldsb[(tile-1)&1] ready (written pre-B0)
        if (tile + 1 < 32) {
            const float* xt = xb + (size_t)(tile + 1) * 4096;
            v0 = *(const float4*)(xt + r0 * 64 + fc * 4);
            v1 = *(const float4*)(xt + (r0 + 32) * 64 + fc * 4);
        }
        if (tile > 0)  // MFMA on previous tile's buffer, overlaps convert VALU
            gram_step(ldsb + ((tile - 1) & 1) * 8192, lane, cA0, cB0, cA1, cB1, has2, acc0, acc1);
        // convert + moments + 7-bit coarse hist: channel c2, rows 8g..8g+7
        char* cb = ldsb + (tile & 1) * 8192;
        uint32_t pk[4];
#pragma unroll
        for (int j2 = 0; j2 < 4; ++j2) {
            float a0 = lds_f[(g * 8 + 2 * j2) * 64 + c2];
            float a1 = lds_f[(g * 8 + 2 * j2 + 1) * 64 + c2];
            S1 += a0 + a1;
            float q0 = a0 * a0, q1 = a1 * a1;
            S2 += q0 + q1;
            S3 += q0 * a0 + q1 * a1;
            S4 += q0 * q0 + q1 * q1;
            mx = fmaxf(mx, fmaxf(a0, a1));
            mn = fminf(mn, fminf(a0, a1));
            uint32_t u0 = f2bf(a0), u1 = f2bf(a1);
            pk[j2] = u0 | (u1 << 16);
            uint32_t k0 = (u0 & 0x8000u) ? ((~u0) & 0xFFFFu) : (u0 | 0x8000u);
            uint32_t k1 = (u1 & 0x8000u) ? ((~u1) & 0xFFFFu) : (u1 | 0x8000u);
            uint32_t b0 = k0 >> 9, b1v = k1 >> 9;
            atomicAdd(&histP[c2 * 65 + (b0 >> 1)], 1u << ((b0 & 1) * 16));
            atomicAdd(&histP[c2 * 65 + (b1v >> 1)], 1u << ((b1v & 1) * 16));
        }
        uint4 pkv = make_uint4(pk[0], pk[1], pk[2], pk[3]);
        *(uint4*)(cb + (uint32_t)(c2 * 128) + (((uint32_t)(g * 16)) ^ swz)) = pkv;
        __syncthreads();  // B0 for next iter
    }
    // final MFMA on tile 31's buffer (parity 1); barrier already passed post-write
    gram_step(ldsb + 8192, lane, cA0, cB0, cA1, cB1, has2, acc0, acc1);
    __syncthreads();  // before aliasing Gs over ldsb

    // Gram tiles -> Gs (D layout: col=lane&15, row=4*(lane>>4)+reg)
    {
        const int r15 = lane & 15, rq = lane >> 4;
#pragma unroll
        for (int r = 0; r < 4; ++r)
            Gs[(ci0 * 16 + rq * 4 + r) * 64 + di0 * 16 + r15] = acc0[r];
        if (has2) {
#pragma unroll
            for (int r = 0; r < 4; ++r)
                Gs[(ci1 * 16 + rq * 4 + r) * 64 + di1 * 16 + r15] = acc1[r];
        }
    }
    red[(g * 6 + 0) * 64 + c2] = S1;
    red[(g * 6 + 1) * 64 + c2] = S2;
    red[(g * 6 + 2) * 64 + c2] = S3;
    red[(g * 6 + 3) * 64 + c2] = S4;
    red[(g * 6 + 4) * 64 + c2] = mx;
    red[(g * 6 + 5) * 64 + c2] = mn;
    __syncthreads();

    if (tid < 64) {
        float s1 = 0.f, s2 = 0.f, s3 = 0.f, s4 = 0.f, ma = -INFINITY, mi = INFINITY;
#pragma unroll
        for (int gg = 0; gg < 8; ++gg) {
            s1 += red[(gg * 6 + 0) * 64 + tid];
            s2 += red[(gg * 6 + 1) * 64 + tid];
            s3 += red[(gg * 6 + 2) * 64 + tid];
            s4 += red[(gg * 6 + 3) * 64 + tid];
            ma = fmaxf(ma, red[(gg * 6 + 4) * 64 + tid]);
            mi = fminf(mi, red[(gg * 6 + 5) * 64 + tid]);
        }
        const float Tf = 2048.0f;
        float mu = s1 / Tf;
        float css = fmaxf(s2 - Tf * mu * mu, 0.f);
        float sd = sqrtf(css / (Tf - 1.f));
        float m3 = (s3 - 3.f * mu * s2 + 2.f * Tf * mu * mu * mu) / Tf;
        float m4 = (s4 - 4.f * mu * s3 + 6.f * mu * mu * s2 - 3.f * Tf * mu * mu * mu * mu) / Tf;
        float skew = m3 / (sd * sd * sd + EPSF);
        float kurt = m4 / (sd * sd * sd * sd + EPSF);
        float cv = sd / (fabsf(mu) + EPSF);
        float* fb = feats + (size_t)b * 2528;
        fb[tid] = mu; fb[64 + tid] = sd; fb[128 + tid] = ma; fb[192 + tid] = mi;
        fb[320 + tid] = skew; fb[384 + tid] = kurt; fb[448 + tid] = cv;
        mu_s[tid] = mu; is_s[tid] = 1.f / (sd + EPSF);
        // coarse selection: rank 1023 over 128 packed bins
        int k = 1023, bin = -1;
        for (int bq = 0; bq < 64; ++bq) {
            uint32_t wd = histP[tid * 65 + bq];
            int c0n = (int)(wd & 0xFFFFu), c1n = (int)(wd >> 16);
            if (bin < 0) {
                if (k < c0n) bin = 2 * bq;
                else { k -= c0n; if (k < c1n) bin = 2 * bq + 1; else k -= c1n; }
            }
        }
        sel[b * 64 + tid] = make_uint2((uint32_t)bin, (uint32_t)k);
    }
    __syncthreads();

    for (int p = tid; p < 2016; p += 512) {
        int i = 0;
        while ((i + 1) * 63 - ((i + 1) * i) / 2 <= p) ++i;
        int j = i + 1 + (p - (i * 63 - (i * (i - 1)) / 2));
        float num = Gs[i * 64 + j] - 2048.0f * mu_s[i] * mu_s[j];
        float cr = num * is_s[i] * is_s[j] * (1.0f / 2047.0f);
        feats[(size_t)b * 2528 + 512 + p] = cr;
    }
}

// ---------------------------------------------------------------------------
// K2: median fine pass — coalesced scan, 9-bit predicated fine histogram
// grid 512, 512 threads, 65.8 KB LDS
// ---------------------------------------------------------------------------
__global__ __launch_bounds__(512) void k2_median(const float* __restrict__ x,
                                                 const uint2* __restrict__ sel,
                                                 float* __restrict__ feats) {
    const int b = blockIdx.x;
    const int tid = threadIdx.x;
    __shared__ uint32_t fh[64 * 257];   // 512 fine bins packed 2x u16
    __shared__ uint32_t selB_s[64], rank_s[64];

    for (int i = tid; i < 64 * 257; i += 512) fh[i] = 0u;
    if (tid < 64) {
        uint2 s = sel[b * 64 + tid];
        selB_s[tid] = s.x; rank_s[tid] = s.y;
    }
    __syncthreads();

    const int fc = tid & 15, r0 = tid >> 4;
    const float* xb = x + (size_t)b * (2048 * 64);
    const uint32_t sb0 = selB_s[fc * 4 + 0], sb1 = selB_s[fc * 4 + 1];
    const uint32_t sb2 = selB_s[fc * 4 + 2], sb3 = selB_s[fc * 4 + 3];

    for (int i = 0; i < 64; ++i) {
        float4 v = *(const float4*)(xb + (size_t)(r0 + 32 * i) * 64 + fc * 4);
#pragma unroll
        for (int cc = 0; cc < 4; ++cc) {
            float vf = (cc == 0) ? v.x : (cc == 1) ? v.y : (cc == 2) ? v.z : v.w;
            uint32_t sb = (cc == 0) ? sb0 : (cc == 1) ? sb1 : (cc == 2) ? sb2 : sb3;
            uint32_t u = f2bf(vf);
            uint32_t k = (u & 0x8000u) ? ((~u) & 0xFFFFu) : (u | 0x8000u);
            if ((k >> 9) == sb) {
                uint32_t fb = k & 511u;
                atomicAdd(&fh[(fc * 4 + cc) * 257 + (fb >> 1)], 1u << ((fb & 1u) * 16));
            }
        }
    }
    __syncthreads();

    if (tid < 64) {
        int k = (int)rank_s[tid], bin = -1;
        for (int bq = 0; bq < 256; ++bq) {
            uint32_t wd = fh[tid * 257 + bq];
            int c0n = (int)(wd & 0xFFFFu), c1n = (int)(wd >> 16);
            if (bin < 0) {
                if (k < c0n) bin = 2 * bq;
                else { k -= c0n; if (k < c1n) bin = 2 * bq + 1; else k -= c1n; }
            }
        }
        uint32_t key16 = (selB_s[tid] << 9) | (uint32_t)bin;
        uint32_t bf = (key16 & 0x8000u) ? (key16 ^ 0x8000u) : ((~key16) & 0xFFFFu);
        feats[(size_t)b * 2528 + 256 + tid] = __builtin_bit_cast(float, bf << 16);
    }
}

// ---------------------------------------------------------------------------
// K3: h1-partial = feats @ W1^T, fp32, K-major swizzled LDS, b128 reads,
// 64x64 tiles, 4x4/thread, k-split z=8. grid (8,8,8)
// ---------------------------------------------------------------------------
__global__ __launch_bounds__(256, 2) void k3_gemm1(const float* __restrict__ feats,
                                                   const float* __restrict__ W1,
                                                   float* __restrict__ C1p) {
    const int jt = blockIdx.x, bt = blockIdx.y, z = blockIdx.z;
    const int tid = threadIdx.x;
    __shared__ float As[32 * 64], Bs[32 * 64];   // [kk][r], col XOR-swizzled
    const int k0 = z * 320;
    const int klen = (z == 7) ? 288 : 320;
    const int tx = tid & 15, ty = tid >> 4;
    float acc[4][4] = {};

    for (int kc = k0; kc < k0 + klen; kc += 32) {
        __syncthreads();
#pragma unroll
        for (int i = 0; i < 2; ++i) {
            int f = tid + (i << 8);
            int r = f >> 3;
            int c4 = (f & 7) << 2;
            f32x4 va = *(const f32x4*)(feats + (size_t)(bt * 64 + r) * 2528 + kc + c4);
            f32x4 vb = *(const f32x4*)(W1 + (size_t)(jt * 64 + r) * 2528 + kc + c4);
#pragma unroll
            for (int j = 0; j < 4; ++j) {
                int kk = c4 + j;
                int rs = r ^ ((kk & 7) << 2);
                As[kk * 64 + rs] = va[j];
                Bs[kk * 64 + rs] = vb[j];
            }
        }
        __syncthreads();
#pragma unroll
        for (int kk = 0; kk < 32; ++kk) {
            const int sw = (kk & 7) << 2;
            f32x4 a = *(const f32x4*)&As[kk * 64 + ((ty * 4) ^ sw)];
            f32x4 bb = *(const f32x4*)&Bs[kk * 64 + ((tx * 4) ^ sw)];
#pragma unroll
            for (int m = 0; m < 4; ++m)
#pragma unroll
                for (int n = 0; n < 4; ++n)
                    acc[m][n] += a[m] * bb[n];
        }
    }
    float* dst = C1p + (size_t)z * 262144;
#pragma unroll
    for (int m = 0; m < 4; ++m) {
        float4 o = make_float4(acc[m][0], acc[m][1], acc[m][2], acc[m][3]);
        *(float4*)(dst + (size_t)(bt * 64 + ty * 4 + m) * 512 + jt * 64 + tx * 4) = o;
    }
}

// ---------------------------------------------------------------------------
// K4: h2 = relu(sum_z C1p + b1) @ W2^T + b2, then LayerNorm. grid 64
// ---------------------------------------------------------------------------
__global__ __launch_bounds__(256) void k4_gemm2_ln(const float* __restrict__ C1p,
                                                   const float* __restrict__ b1,
                                                   const float* __restrict__ W2,
                                                   const float* __restrict__ b2,
                                                   const float* __restrict__ gamma,
                                                   const float* __restrict__ beta,
                                                   float* __restrict__ out) {
    const int bt = blockIdx.x;
    const int tid = threadIdx.x;
    __shared__ float h1s[8][512];
    __shared__ float W2s[256][33];
    __shared__ float h2s[8][256];
    __shared__ float mu_s[8], rs_s[8];

#pragma unroll
    for (int m = 0; m < 16; ++m) {
        int idx = tid + (m << 8);
        int r = idx >> 9, k = idx & 511;
        size_t base = (size_t)(bt * 8 + r) * 512 + k;
        float v = b1[k];
#pragma unroll
        for (int s = 0; s < 8; ++s) v += C1p[(size_t)s * 262144 + base];
        h1s[r][k] = fmaxf(v, 0.f);
    }
    float acc[8] = {};
    for (int kc = 0; kc < 512; kc += 32) {
        __syncthreads();
#pragma unroll
        for (int i = 0; i < 8; ++i) {
            int f = tid + (i << 8);
            int row = f >> 3, c4 = (f & 7) << 2;
            float4 v = *(const float4*)(W2 + (size_t)row * 512 + kc + c4);
            W2s[row][c4] = v.x; W2s[row][c4 + 1] = v.y; W2s[row][c4 + 2] = v.z; W2s[row][c4 + 3] = v.w;
        }
        __syncthreads();
#pragma unroll
        for (int kk = 0; kk < 32; ++kk) {
            float wv = W2s[tid][kk];
#pragma unroll
            for (int r = 0; r < 8; ++r) acc[r] += h1s[r][kc + kk] * wv;
        }
    }
    float bv = b2[tid];
    __syncthreads();
#pragma unroll
    for (int r = 0; r < 8; ++r) h2s[r][tid] = acc[r] + bv;
    __syncthreads();
    {
        int r = tid >> 5, l5 = tid & 31;
        float sum = 0.f;
#pragma unroll
        for (int jj = 0; jj < 8; ++jj) sum += h2s[r][l5 + jj * 32];
#pragma unroll
        for (int m = 16; m >= 1; m >>= 1) sum += __shfl_xor(sum, m);
        if (l5 == 0) mu_s[r] = sum * (1.0f / 256.0f);
    }
    __syncthreads();
    {
        int r = tid >> 5, l5 = tid & 31;
        float mu = mu_s[r];
        float sq = 0.f;
#pragma unroll
        for (int jj = 0; jj < 8; ++jj) { float d = h2s[r][l5 + jj * 32] - mu; sq += d * d; }
#pragma unroll
        for (int m = 16; m >= 1; m >>= 1) sq += __shfl_xor(sq, m);
        if (l5 == 0) rs_s[r] = rsqrtf(sq * (1.0f / 256.0f) + 1e-5f);
    }
    __syncthreads();
    float g = gamma[tid], be = beta[tid];
#pragma unroll
    for (int r = 0; r < 8; ++r) {
        float v = (h2s[r][tid] - mu_s[r]) * rs_s[r] * g + be;
        out[(size_t)(bt * 8 + r) * 256 + tid] = v;
    }
}

extern "C" void kernel_launch(void* const* d_in, const int* in_sizes, int n_in,
                              void* d_out, int out_size, void* d_ws, size_t ws_size,
                              hipStream_t stream) {
    const float* x = (const float*)d_in[0];
    const float* W1 = (const float*)d_in[1];
    const float* b1 = (const float*)d_in[2];
    const float* W2 = (const float*)d_in[3];
    const float* b2 = (const float*)d_in[4];
    const float* gamma = (const float*)d_in[5];
    const float* beta = (const float*)d_in[6];

    float* feats = (float*)d_ws;                       // 512 x 2528 fp32
    float* C1p = feats + (size_t)512 * 2528;           // 8 x 512 x 512 fp32
    uint2* sel = (uint2*)(C1p + (size_t)8 * 512 * 512);
    float* out = (float*)d_out;

    k1_stats_gram<<<dim3(512), dim3(512), 0, stream>>>(x, feats, sel);
    k2_median<<<dim3(512), dim3(512), 0, stream>>>(x, sel, feats);
    k3_gemm1<<<dim3(8, 8, 8), dim3(256), 0, stream>>>(feats, W1, C1p);
    k4_gemm2_ln<<<dim3(64), dim3(256), 0, stream>>>(C1p, b1, W2, b2, gamma, beta, out);
}

// Round 4
// 263.296 us; speedup vs baseline: 1.6268x; 1.0124x over previous
//
#include <hip/hip_runtime.h>
#include <stdint.h>

#define EPSF 1e-8f

typedef __attribute__((ext_vector_type(4))) float f32x4;
typedef __attribute__((ext_vector_type(8))) short s16x8;

__device__ __forceinline__ uint32_t f2bf(float f) {
    uint32_t u = __builtin_bit_cast(uint32_t, f);
    return (u + 0x7FFFu + ((u >> 16) & 1u)) >> 16;  // RNE fp32 -> bf16 bits
}

__device__ __forceinline__ void gram_step(const char* pb, int lane,
                                          int cA0, int cB0, int cA1, int cB1, bool has2,
                                          f32x4& acc0, f32x4& acc1) {
#pragma unroll
    for (int kb = 0; kb < 2; ++kb) {
        const uint32_t tb = (uint32_t)(16 * (lane >> 4) + 64 * kb);
        s16x8 af = *(const s16x8*)(pb + (uint32_t)(cA0 * 128) + (tb ^ (uint32_t)((cA0 & 7) << 4)));
        s16x8 bf = *(const s16x8*)(pb + (uint32_t)(cB0 * 128) + (tb ^ (uint32_t)((cB0 & 7) << 4)));
        acc0 = __builtin_amdgcn_mfma_f32_16x16x32_bf16(af, bf, acc0, 0, 0, 0);
        if (has2) {
            s16x8 af1 = *(const s16x8*)(pb + (uint32_t)(cA1 * 128) + (tb ^ (uint32_t)((cA1 & 7) << 4)));
            s16x8 bf1 = *(const s16x8*)(pb + (uint32_t)(cB1 * 128) + (tb ^ (uint32_t)((cB1 & 7) << 4)));
            acc1 = __builtin_amdgcn_mfma_f32_16x16x32_bf16(af1, bf1, acc1, 0, 0, 0);
        }
    }
}

// ---------------------------------------------------------------------------
// K1: direct-register moments + bf16 convert + coarse hist + MFMA Gram.
// No fp32 LDS staging (channel dim is contiguous -> per-channel access is
// coalesced). 1 barrier/tile, dbuf bf16 tile. grid 512, 512 thr, 44.8 KB LDS.
// ---------------------------------------------------------------------------
__global__ __launch_bounds__(512, 4) void k1_stats_gram(const float* __restrict__ x,
                                                        float* __restrict__ feats,
                                                        uint2* __restrict__ sel) {
    const int b = blockIdx.x;
    const int tid = threadIdx.x;
    const int lane = tid & 63;

    __shared__ __align__(16) char smem[45824];
    char* ldsb = smem;                              // 2 x 8192 B bf16 [c][t] swizzled
    uint32_t* histP = (uint32_t*)(smem + 16384);    // [64][65] packed 2x u16 bins
    float* red = (float*)(smem + 33024);            // [8][6][64]
    float* mu_s = (float*)(smem + 45312);
    float* is_s = (float*)(smem + 45568);
    float* Gs = (float*)smem;                       // post-loop alias over ldsb [64][64]

    for (int i = tid; i < 64 * 65; i += 512) histP[i] = 0u;

    const int c2 = tid & 63, g = tid >> 6;
    const uint32_t swz = (uint32_t)((c2 & 7) << 4);

    // Gram upper-tri 4x4 tile-grid enumeration (10 tiles over 8 waves)
    const uint32_t ciPack = 0xE9500u;  // {0,0,0,0,1,1,1,2,2,3}
    const uint32_t diPack = 0xFB9E4u;  // {0,1,2,3,1,2,3,2,3,3}
    const int w = tid >> 6;
    const int ci0 = (ciPack >> (2 * w)) & 3, di0 = (diPack >> (2 * w)) & 3;
    const bool has2 = (w < 2);
    const int idx1 = 8 + w;
    const int ci1 = (ciPack >> (2 * idx1)) & 3, di1 = (diPack >> (2 * idx1)) & 3;
    const int cA0 = ci0 * 16 + (lane & 15), cB0 = di0 * 16 + (lane & 15);
    const int cA1 = ci1 * 16 + (lane & 15), cB1 = di1 * 16 + (lane & 15);
    f32x4 acc0 = {0.f, 0.f, 0.f, 0.f};
    f32x4 acc1 = {0.f, 0.f, 0.f, 0.f};

    float S1 = 0.f, S2 = 0.f, S3 = 0.f, S4 = 0.f;
    float mx = -INFINITY, mn = INFINITY;

    // thread reads column c2, rows tile*64 + g*8 + j  (lanes = channels -> coalesced)
    const float* xc = x + (size_t)b * (2048 * 64) + (size_t)(g * 8) * 64 + c2;
    float cur[8], nxt[8];
#pragma unroll
    for (int j = 0; j < 8; ++j) cur[j] = xc[j * 64];
    __syncthreads();  // histP clear complete

    for (int tile = 0; tile < 32; ++tile) {
        if (tile + 1 < 32) {
            const float* xt = xc + (size_t)(tile + 1) * 4096;
#pragma unroll
            for (int j = 0; j < 8; ++j) nxt[j] = xt[j * 64];
        }
        uint32_t pk[4];
#pragma unroll
        for (int j2 = 0; j2 < 4; ++j2) {
            float a0 = cur[2 * j2], a1 = cur[2 * j2 + 1];
            S1 += a0 + a1;
            float q0 = a0 * a0, q1 = a1 * a1;
            S2 += q0 + q1;
            S3 += q0 * a0 + q1 * a1;
            S4 += q0 * q0 + q1 * q1;
            mx = fmaxf(mx, fmaxf(a0, a1));
            mn = fminf(mn, fminf(a0, a1));
            uint32_t u0 = f2bf(a0), u1 = f2bf(a1);
            pk[j2] = u0 | (u1 << 16);
            uint32_t k0 = (u0 & 0x8000u) ? ((~u0) & 0xFFFFu) : (u0 | 0x8000u);
            uint32_t k1 = (u1 & 0x8000u) ? ((~u1) & 0xFFFFu) : (u1 | 0x8000u);
            uint32_t b0 = k0 >> 9, b1v = k1 >> 9;
            atomicAdd(&histP[c2 * 65 + (b0 >> 1)], 1u << ((b0 & 1) * 16));
            atomicAdd(&histP[c2 * 65 + (b1v >> 1)], 1u << ((b1v & 1) * 16));
        }
        char* cb = ldsb + (tile & 1) * 8192;
        *(uint4*)(cb + (uint32_t)(c2 * 128) + (((uint32_t)(g * 16)) ^ swz)) =
            make_uint4(pk[0], pk[1], pk[2], pk[3]);
        __syncthreads();  // cb ready for all; also orders reuse of this buffer (see dbuf note)
        gram_step(cb, lane, cA0, cB0, cA1, cB1, has2, acc0, acc1);
#pragma unroll
        for (int j = 0; j < 8; ++j) cur[j] = nxt[j];
    }
    __syncthreads();  // gram reads done everywhere; Gs may alias ldsb

    // Gram tiles -> Gs (D layout: col=lane&15, row=4*(lane>>4)+reg)
    {
        const int r15 = lane & 15, rq = lane >> 4;
#pragma unroll
        for (int r = 0; r < 4; ++r)
            Gs[(ci0 * 16 + rq * 4 + r) * 64 + di0 * 16 + r15] = acc0[r];
        if (has2) {
#pragma unroll
            for (int r = 0; r < 4; ++r)
                Gs[(ci1 * 16 + rq * 4 + r) * 64 + di1 * 16 + r15] = acc1[r];
        }
    }
    red[(g * 6 + 0) * 64 + c2] = S1;
    red[(g * 6 + 1) * 64 + c2] = S2;
    red[(g * 6 + 2) * 64 + c2] = S3;
    red[(g * 6 + 3) * 64 + c2] = S4;
    red[(g * 6 + 4) * 64 + c2] = mx;
    red[(g * 6 + 5) * 64 + c2] = mn;
    __syncthreads();

    if (tid < 64) {
        float s1 = 0.f, s2 = 0.f, s3 = 0.f, s4 = 0.f, ma = -INFINITY, mi = INFINITY;
#pragma unroll
        for (int gg = 0; gg < 8; ++gg) {
            s1 += red[(gg * 6 + 0) * 64 + tid];
            s2 += red[(gg * 6 + 1) * 64 + tid];
            s3 += red[(gg * 6 + 2) * 64 + tid];
            s4 += red[(gg * 6 + 3) * 64 + tid];
            ma = fmaxf(ma, red[(gg * 6 + 4) * 64 + tid]);
            mi = fminf(mi, red[(gg * 6 + 5) * 64 + tid]);
        }
        const float Tf = 2048.0f;
        float mu = s1 / Tf;
        float css = fmaxf(s2 - Tf * mu * mu, 0.f);
        float sd = sqrtf(css / (Tf - 1.f));
        float m3 = (s3 - 3.f * mu * s2 + 2.f * Tf * mu * mu * mu) / Tf;
        float m4 = (s4 - 4.f * mu * s3 + 6.f * mu * mu * s2 - 3.f * Tf * mu * mu * mu * mu) / Tf;
        float skew = m3 / (sd * sd * sd + EPSF);
        float kurt = m4 / (sd * sd * sd * sd + EPSF);
        float cv = sd / (fabsf(mu) + EPSF);
        float* fb = feats + (size_t)b * 2528;
        fb[tid] = mu; fb[64 + tid] = sd; fb[128 + tid] = ma; fb[192 + tid] = mi;
        fb[320 + tid] = skew; fb[384 + tid] = kurt; fb[448 + tid] = cv;
        mu_s[tid] = mu; is_s[tid] = 1.f / (sd + EPSF);
        // coarse selection: rank 1023 over 128 packed bins
        int k = 1023, bin = -1;
        for (int bq = 0; bq < 64; ++bq) {
            uint32_t wd = histP[tid * 65 + bq];
            int c0n = (int)(wd & 0xFFFFu), c1n = (int)(wd >> 16);
            if (bin < 0) {
                if (k < c0n) bin = 2 * bq;
                else { k -= c0n; if (k < c1n) bin = 2 * bq + 1; else k -= c1n; }
            }
        }
        sel[b * 64 + tid] = make_uint2((uint32_t)bin, (uint32_t)k);
    }
    __syncthreads();

    for (int p = tid; p < 2016; p += 512) {
        int i = 0;
        while ((i + 1) * 63 - ((i + 1) * i) / 2 <= p) ++i;
        int j = i + 1 + (p - (i * 63 - (i * (i - 1)) / 2));
        float num = Gs[i * 64 + j] - 2048.0f * mu_s[i] * mu_s[j];
        float cr = num * is_s[i] * is_s[j] * (1.0f / 2047.0f);
        feats[(size_t)b * 2528 + 512 + p] = cr;
    }
}

// ---------------------------------------------------------------------------
// K2: median fine pass — coalesced scan, 9-bit predicated fine histogram
// grid 512, 512 threads, 65.8 KB LDS
// ---------------------------------------------------------------------------
__global__ __launch_bounds__(512) void k2_median(const float* __restrict__ x,
                                                 const uint2* __restrict__ sel,
                                                 float* __restrict__ feats) {
    const int b = blockIdx.x;
    const int tid = threadIdx.x;
    __shared__ uint32_t fh[64 * 257];   // 512 fine bins packed 2x u16
    __shared__ uint32_t selB_s[64], rank_s[64];

    for (int i = tid; i < 64 * 257; i += 512) fh[i] = 0u;
    if (tid < 64) {
        uint2 s = sel[b * 64 + tid];
        selB_s[tid] = s.x; rank_s[tid] = s.y;
    }
    __syncthreads();

    const int fc = tid & 15, r0 = tid >> 4;
    const float* xb = x + (size_t)b * (2048 * 64);
    const uint32_t sb0 = selB_s[fc * 4 + 0], sb1 = selB_s[fc * 4 + 1];
    const uint32_t sb2 = selB_s[fc * 4 + 2], sb3 = selB_s[fc * 4 + 3];

    for (int i = 0; i < 64; ++i) {
        float4 v = *(const float4*)(xb + (size_t)(r0 + 32 * i) * 64 + fc * 4);
#pragma unroll
        for (int cc = 0; cc < 4; ++cc) {
            float vf = (cc == 0) ? v.x : (cc == 1) ? v.y : (cc == 2) ? v.z : v.w;
            uint32_t sb = (cc == 0) ? sb0 : (cc == 1) ? sb1 : (cc == 2) ? sb2 : sb3;
            uint32_t u = f2bf(vf);
            uint32_t k = (u & 0x8000u) ? ((~u) & 0xFFFFu) : (u | 0x8000u);
            if ((k >> 9) == sb) {
                uint32_t fb = k & 511u;
                atomicAdd(&fh[(fc * 4 + cc) * 257 + (fb >> 1)], 1u << ((fb & 1u) * 16));
            }
        }
    }
    __syncthreads();

    if (tid < 64) {
        int k = (int)rank_s[tid], bin = -1;
        for (int bq = 0; bq < 256; ++bq) {
            uint32_t wd = fh[tid * 257 + bq];
            int c0n = (int)(wd & 0xFFFFu), c1n = (int)(wd >> 16);
            if (bin < 0) {
                if (k < c0n) bin = 2 * bq;
                else { k -= c0n; if (k < c1n) bin = 2 * bq + 1; else k -= c1n; }
            }
        }
        uint32_t key16 = (selB_s[tid] << 9) | (uint32_t)bin;
        uint32_t bf = (key16 & 0x8000u) ? (key16 ^ 0x8000u) : ((~key16) & 0xFFFFu);
        feats[(size_t)b * 2528 + 256 + tid] = __builtin_bit_cast(float, bf << 16);
    }
}

// ---------------------------------------------------------------------------
// K3: h1-partial = feats @ W1^T, fp32, K-major swizzled LDS, b128 reads,
// 64x64 tiles, 4x4/thread, k-split z=8. grid (8,8,8)
// ---------------------------------------------------------------------------
__global__ __launch_bounds__(256, 2) void k3_gemm1(const float* __restrict__ feats,
                                                   const float* __restrict__ W1,
                                                   float* __restrict__ C1p) {
    const int jt = blockIdx.x, bt = blockIdx.y, z = blockIdx.z;
    const int tid = threadIdx.x;
    __shared__ float As[32 * 64], Bs[32 * 64];   // [kk][r], col XOR-swizzled
    const int k0 = z * 320;
    const int klen = (z == 7) ? 288 : 320;
    const int tx = tid & 15, ty = tid >> 4;
    float acc[4][4] = {};

    for (int kc = k0; kc < k0 + klen; kc += 32) {
        __syncthreads();
#pragma unroll
        for (int i = 0; i < 2; ++i) {
            int f = tid + (i << 8);
            int r = f >> 3;
            int c4 = (f & 7) << 2;
            f32x4 va = *(const f32x4*)(feats + (size_t)(bt * 64 + r) * 2528 + kc + c4);
            f32x4 vb = *(const f32x4*)(W1 + (size_t)(jt * 64 + r) * 2528 + kc + c4);
#pragma unroll
            for (int j = 0; j < 4; ++j) {
                int kk = c4 + j;
                int rs = r ^ ((kk & 7) << 2);
                As[kk * 64 + rs] = va[j];
                Bs[kk * 64 + rs] = vb[j];
            }
        }
        __syncthreads();
#pragma unroll
        for (int kk = 0; kk < 32; ++kk) {
            const int sw = (kk & 7) << 2;
            f32x4 a = *(const f32x4*)&As[kk * 64 + ((ty * 4) ^ sw)];
            f32x4 bb = *(const f32x4*)&Bs[kk * 64 + ((tx * 4) ^ sw)];
#pragma unroll
            for (int m = 0; m < 4; ++m)
#pragma unroll
                for (int n = 0; n < 4; ++n)
                    acc[m][n] += a[m] * bb[n];
        }
    }
    float* dst = C1p + (size_t)z * 262144;
#pragma unroll
    for (int m = 0; m < 4; ++m) {
        float4 o = make_float4(acc[m][0], acc[m][1], acc[m][2], acc[m][3]);
        *(float4*)(dst + (size_t)(bt * 64 + ty * 4 + m) * 512 + jt * 64 + tx * 4) = o;
    }
}

// ---------------------------------------------------------------------------
// K4: h2 = relu(sum_z C1p + b1) @ W2^T + b2, then LayerNorm. grid 64
// ---------------------------------------------------------------------------
__global__ __launch_bounds__(256) void k4_gemm2_ln(const float* __restrict__ C1p,
                                                   const float* __restrict__ b1,
                                                   const float* __restrict__ W2,
                                                   const float* __restrict__ b2,
                                                   const float* __restrict__ gamma,
                                                   const float* __restrict__ beta,
                                                   float* __restrict__ out) {
    const int bt = blockIdx.x;
    const int tid = threadIdx.x;
    __shared__ float h1s[8][512];
    __shared__ float W2s[256][33];
    __shared__ float h2s[8][256];
    __shared__ float mu_s[8], rs_s[8];

#pragma unroll
    for (int m = 0; m < 16; ++m) {
        int idx = tid + (m << 8);
        int r = idx >> 9, k = idx & 511;
        size_t base = (size_t)(bt * 8 + r) * 512 + k;
        float v = b1[k];
#pragma unroll
        for (int s = 0; s < 8; ++s) v += C1p[(size_t)s * 262144 + base];
        h1s[r][k] = fmaxf(v, 0.f);
    }
    float acc[8] = {};
    for (int kc = 0; kc < 512; kc += 32) {
        __syncthreads();
#pragma unroll
        for (int i = 0; i < 8; ++i) {
            int f = tid + (i << 8);
            int row = f >> 3, c4 = (f & 7) << 2;
            float4 v = *(const float4*)(W2 + (size_t)row * 512 + kc + c4);
            W2s[row][c4] = v.x; W2s[row][c4 + 1] = v.y; W2s[row][c4 + 2] = v.z; W2s[row][c4 + 3] = v.w;
        }
        __syncthreads();
#pragma unroll
        for (int kk = 0; kk < 32; ++kk) {
            float wv = W2s[tid][kk];
#pragma unroll
            for (int r = 0; r < 8; ++r) acc[r] += h1s[r][kc + kk] * wv;
        }
    }
    float bv = b2[tid];
    __syncthreads();
#pragma unroll
    for (int r = 0; r < 8; ++r) h2s[r][tid] = acc[r] + bv;
    __syncthreads();
    {
        int r = tid >> 5, l5 = tid & 31;
        float sum = 0.f;
#pragma unroll
        for (int jj = 0; jj < 8; ++jj) sum += h2s[r][l5 + jj * 32];
#pragma unroll
        for (int m = 16; m >= 1; m >>= 1) sum += __shfl_xor(sum, m);
        if (l5 == 0) mu_s[r] = sum * (1.0f / 256.0f);
    }
    __syncthreads();
    {
        int r = tid >> 5, l5 = tid & 31;
        float mu = mu_s[r];
        float sq = 0.f;
#pragma unroll
        for (int jj = 0; jj < 8; ++jj) { float d = h2s[r][l5 + jj * 32] - mu; sq += d * d; }
#pragma unroll
        for (int m = 16; m >= 1; m >>= 1) sq += __shfl_xor(sq, m);
        if (l5 == 0) rs_s[r] = rsqrtf(sq * (1.0f / 256.0f) + 1e-5f);
    }
    __syncthreads();
    float g = gamma[tid], be = beta[tid];
#pragma unroll
    for (int r = 0; r < 8; ++r) {
        float v = (h2s[r][tid] - mu_s[r]) * rs_s[r] * g + be;
        out[(size_t)(bt * 8 + r) * 256 + tid] = v;
    }
}

extern "C" void kernel_launch(void* const* d_in, const int* in_sizes, int n_in,
                              void* d_out, int out_size, void* d_ws, size_t ws_size,
                              hipStream_t stream) {
    const float* x = (const float*)d_in[0];
    const float* W1 = (const float*)d_in[1];
    const float* b1 = (const float*)d_in[2];
    const float* W2 = (const float*)d_in[3];
    const float* b2 = (const float*)d_in[4];
    const float* gamma = (const float*)d_in[5];
    const float* beta = (const float*)d_in[6];

    float* feats = (float*)d_ws;                       // 512 x 2528 fp32
    float* C1p = feats + (size_t)512 * 2528;           // 8 x 512 x 512 fp32
    uint2* sel = (uint2*)(C1p + (size_t)8 * 512 * 512);
    float* out = (float*)d_out;

    k1_stats_gram<<<dim3(512), dim3(512), 0, stream>>>(x, feats, sel);
    k2_median<<<dim3(512), dim3(512), 0, stream>>>(x, sel, feats);
    k3_gemm1<<<dim3(8, 8, 8), dim3(256), 0, stream>>>(feats, W1, C1p);
    k4_gemm2_ln<<<dim3(64), dim3(256), 0, stream>>>(C1p, b1, W2, b2, gamma, beta, out);
}